// Round 10
// baseline (299.862 us; speedup 1.0000x reference)
//
#include <hip/hip_runtime.h>
#include <hip/hip_bf16.h>
#include <stdint.h>

#define TOKENS 8192
#define IN_F   4096
#define OUT_F  4096

typedef __attribute__((ext_vector_type(4))) float  f32x4;
typedef __attribute__((ext_vector_type(8))) __bf16 bf16x8;

__device__ __forceinline__ unsigned short f2bf(float f) {
    union { float f; uint32_t u; } c; c.f = f;
    uint32_t u = c.u;
    u += 0x7fffu + ((u >> 16) & 1);   // round-to-nearest-even
    return (unsigned short)(u >> 16);
}

__device__ __forceinline__ void load_lds_16(const void* gptr, void* lptr) {
    __builtin_amdgcn_global_load_lds(
        (const __attribute__((address_space(1))) unsigned int*)gptr,
        (__attribute__((address_space(3))) unsigned int*)lptr, 16, 0, 0);
}

// ONE guard per K-tile. Order is WAIT-then-BARRIER: each wave drains its own
// DMA loads, THEN the barrier proves ALL waves' loads landed (tiles are staged
// cooperatively — R9's barrier-first order raced on other waves' rows).
// vmcnt(0) is near-instant: tile T's loads were issued one full body earlier.
__device__ __forceinline__ void tile_bar() {
    asm volatile("s_waitcnt vmcnt(0)\ns_barrier" ::: "memory");
    __builtin_amdgcn_sched_barrier(0);
}
// counted DS wait: oldest reads done, newer stay in flight under MFMA.
// rule #18: sched_barrier(0) so reg-only MFMAs can't hoist above the wait.
template<int N> __device__ __forceinline__ void lgkm() {
    if constexpr (N == 8)      asm volatile("s_waitcnt lgkmcnt(8)" ::: "memory");
    else if constexpr (N == 4) asm volatile("s_waitcnt lgkmcnt(4)" ::: "memory");
    else                       asm volatile("s_waitcnt lgkmcnt(0)" ::: "memory");
    __builtin_amdgcn_sched_barrier(0);
}

// ---------------- merged prep: x->bf16 and W_eff=W*(1+mask)->bf16 ----------------
#define XBLOCKS 2048
#define WBLOCKS 1024
__global__ __launch_bounds__(256) void cvt_kernel(const float* __restrict__ x,
                                                  const float* __restrict__ w,
                                                  const int* __restrict__ mask,
                                                  unsigned short* __restrict__ xb,
                                                  unsigned short* __restrict__ wb) {
    int b = blockIdx.x;
    if (b < XBLOCKS) {
        const int n4 = TOKENS * IN_F / 4;
        int i = b * 256 + threadIdx.x;
        const int stride = XBLOCKS * 256;
        for (; i < n4; i += stride) {
            float4 v = ((const float4*)x)[i];
            ushort4 o;
            o.x = f2bf(v.x); o.y = f2bf(v.y); o.z = f2bf(v.z); o.w = f2bf(v.w);
            ((ushort4*)xb)[i] = o;
        }
    } else {
        const int n4 = OUT_F * IN_F / 4;
        int i = (b - XBLOCKS) * 256 + threadIdx.x;
        const int stride = WBLOCKS * 256;
        for (; i < n4; i += stride) {
            int elem = i * 4;
            int o = elem >> 12;
            int k = elem & (IN_F - 1);
            int mb = mask[(o >> 4) * (IN_F / 16) + (k >> 4)];
            float s = mb ? 2.0f : 1.0f;
            float4 v = ((const float4*)w)[i];
            ushort4 ov;
            ov.x = f2bf(v.x * s); ov.y = f2bf(v.y * s);
            ov.z = f2bf(v.z * s); ov.w = f2bf(v.w * s);
            ((ushort4*)wb)[i] = ov;
        }
    }
}

// ------- 256x256 8-wave, ONE barrier per K-tile, counted-lgkm read-ahead -------
// LDS (shorts): A[buf][ks] at buf*16384 + ks*8192 (256 rows x 32 shorts)
//               B[buf][ks] at 32768 + buf*16384 + ks*8192
// Swizzle: 8-short chunk c XOR (row>>1)&3 (pre-swizzled global source on
// stage, same XOR on fragment read) -> measured-0 conflicts (R3-R8).
#define BM 256
#define BN 256
#define BK 64
#define NT (IN_F / BK)   // 64

#define ST_A(T, H) {                                                           \
    const unsigned short* s_ = srcA + (size_t)(T) * BK + (H) * 32;             \
    unsigned short* d_ = sm + (((T) & 1) * 16384 + (H) * 8192) + dstL;         \
    load_lds_16(s_, d_);                                                       \
    load_lds_16(s_ + (size_t)128 * IN_F, d_ + 4096); }
#define ST_B(T, H) {                                                           \
    const unsigned short* s_ = srcB + (size_t)(T) * BK + (H) * 32;             \
    unsigned short* d_ = sm + (32768 + ((T) & 1) * 16384 + (H) * 8192) + dstL; \
    load_lds_16(s_, d_);                                                       \
    load_lds_16(s_ + (size_t)128 * IN_F, d_ + 4096); }

#define RDB4(R0, R1, R2, R3, BUF, KS) {                                        \
    const unsigned short* p_ = sm + 32768 + (BUF) * 16384 + (KS) * 8192 + b_base; \
    R0 = *(const bf16x8*)(p_);        R1 = *(const bf16x8*)(p_ + 512);         \
    R2 = *(const bf16x8*)(p_ + 1024); R3 = *(const bf16x8*)(p_ + 1536); }

#define RDA4(R0, R1, R2, R3, BUF, KS, MH) {                                    \
    const unsigned short* p_ = sm + (BUF) * 16384 + (KS) * 8192 + (MH) * 2048 + a_base; \
    R0 = *(const bf16x8*)(p_);        R1 = *(const bf16x8*)(p_ + 512);         \
    R2 = *(const bf16x8*)(p_ + 1024); R3 = *(const bf16x8*)(p_ + 1536); }

#define MM16(A0, A1, A2, A3, B0, B1, B2, B3, MH) {                             \
    __builtin_amdgcn_s_setprio(1);                                             \
    acc[(MH)*4+0][0] = __builtin_amdgcn_mfma_f32_16x16x32_bf16(A0, B0, acc[(MH)*4+0][0], 0, 0, 0); \
    acc[(MH)*4+0][1] = __builtin_amdgcn_mfma_f32_16x16x32_bf16(A0, B1, acc[(MH)*4+0][1], 0, 0, 0); \
    acc[(MH)*4+0][2] = __builtin_amdgcn_mfma_f32_16x16x32_bf16(A0, B2, acc[(MH)*4+0][2], 0, 0, 0); \
    acc[(MH)*4+0][3] = __builtin_amdgcn_mfma_f32_16x16x32_bf16(A0, B3, acc[(MH)*4+0][3], 0, 0, 0); \
    acc[(MH)*4+1][0] = __builtin_amdgcn_mfma_f32_16x16x32_bf16(A1, B0, acc[(MH)*4+1][0], 0, 0, 0); \
    acc[(MH)*4+1][1] = __builtin_amdgcn_mfma_f32_16x16x32_bf16(A1, B1, acc[(MH)*4+1][1], 0, 0, 0); \
    acc[(MH)*4+1][2] = __builtin_amdgcn_mfma_f32_16x16x32_bf16(A1, B2, acc[(MH)*4+1][2], 0, 0, 0); \
    acc[(MH)*4+1][3] = __builtin_amdgcn_mfma_f32_16x16x32_bf16(A1, B3, acc[(MH)*4+1][3], 0, 0, 0); \
    acc[(MH)*4+2][0] = __builtin_amdgcn_mfma_f32_16x16x32_bf16(A2, B0, acc[(MH)*4+2][0], 0, 0, 0); \
    acc[(MH)*4+2][1] = __builtin_amdgcn_mfma_f32_16x16x32_bf16(A2, B1, acc[(MH)*4+2][1], 0, 0, 0); \
    acc[(MH)*4+2][2] = __builtin_amdgcn_mfma_f32_16x16x32_bf16(A2, B2, acc[(MH)*4+2][2], 0, 0, 0); \
    acc[(MH)*4+2][3] = __builtin_amdgcn_mfma_f32_16x16x32_bf16(A2, B3, acc[(MH)*4+2][3], 0, 0, 0); \
    acc[(MH)*4+3][0] = __builtin_amdgcn_mfma_f32_16x16x32_bf16(A3, B0, acc[(MH)*4+3][0], 0, 0, 0); \
    acc[(MH)*4+3][1] = __builtin_amdgcn_mfma_f32_16x16x32_bf16(A3, B1, acc[(MH)*4+3][1], 0, 0, 0); \
    acc[(MH)*4+3][2] = __builtin_amdgcn_mfma_f32_16x16x32_bf16(A3, B2, acc[(MH)*4+3][2], 0, 0, 0); \
    acc[(MH)*4+3][3] = __builtin_amdgcn_mfma_f32_16x16x32_bf16(A3, B3, acc[(MH)*4+3][3], 0, 0, 0); \
    __builtin_amdgcn_s_setprio(0); }

// K-tile body (after tile_bar + staging): 4 MFMA clusters, reads one
// cluster ahead via counted lgkm. Ends fully drained (lgkm 0).
#define BODY(BC)                                                               \
  {                                                                            \
    RDB4(bbE0, bbE1, bbE2, bbE3, BC, 0)                                        \
    RDA4(aaE0, aaE1, aaE2, aaE3, BC, 0, 0)                                     \
    RDA4(aaO0, aaO1, aaO2, aaO3, BC, 0, 1)                                     \
    lgkm<4>();                                                                 \
    MM16(aaE0, aaE1, aaE2, aaE3, bbE0, bbE1, bbE2, bbE3, 0)                    \
    RDB4(bbO0, bbO1, bbO2, bbO3, BC, 1)                                        \
    RDA4(aaE0, aaE1, aaE2, aaE3, BC, 1, 0)                                     \
    lgkm<8>();                                                                 \
    MM16(aaO0, aaO1, aaO2, aaO3, bbE0, bbE1, bbE2, bbE3, 1)                    \
    RDA4(aaO0, aaO1, aaO2, aaO3, BC, 1, 1)                                     \
    lgkm<4>();                                                                 \
    MM16(aaE0, aaE1, aaE2, aaE3, bbO0, bbO1, bbO2, bbO3, 0)                    \
    lgkm<0>();                                                                 \
    MM16(aaO0, aaO1, aaO2, aaO3, bbO0, bbO1, bbO2, bbO3, 1)                    \
  }

__global__ __launch_bounds__(512, 2) void gemm8_kernel(const unsigned short* __restrict__ A,
                                                       const unsigned short* __restrict__ B,
                                                       const float* __restrict__ bias,
                                                       float* __restrict__ C) {
    extern __shared__ __align__(16) unsigned short sm[];   // 128KB dynamic

    const int tid  = threadIdx.x;
    const int lane = tid & 63;
    const int wid  = tid >> 6;
    const int wr   = wid >> 2;       // 0..1 -> 128-row span
    const int wc   = wid & 3;        // 0..3 -> 64-col span

    const int nwg = (TOKENS / BM) * (OUT_F / BN);   // 512, %8==0
    int bid = blockIdx.x;
    int swz = (bid & 7) * (nwg >> 3) + (bid >> 3);  // XCD-aware swizzle
    const int tiles_n = OUT_F / BN;                 // 16
    const int t0 = (swz / tiles_n) * BM;
    const int o0 = (swz % tiles_n) * BN;

    // ---- staging constants (pre-swizzled global source, wave-linear dest) ----
    const int srow = tid >> 2;                      // 0..127
    const int sc   = tid & 3;                       // 8-short chunk
    const int scs  = sc ^ ((srow >> 1) & 3);
    const unsigned short* srcA = A + (size_t)(t0 + srow) * IN_F + scs * 8;
    const unsigned short* srcB = B + (size_t)(o0 + srow) * IN_F + scs * 8;
    const int dstL = srow * 32 + sc * 8;

    // ---- fragment-read bases (shorts), same swizzle ----
    const int l15 = lane & 15, q = lane >> 4;
    const int qe = q ^ ((l15 >> 1) & 3);
    const int a_base = (wr * 128 + l15) * 32 + qe * 8;   // + mh*2048 + mf*512
    const int b_base = (wc * 64 + l15) * 32 + qe * 8;    // + nf*512

    f32x4 acc[8][4];
#pragma unroll
    for (int i = 0; i < 8; ++i)
#pragma unroll
        for (int j = 0; j < 4; ++j) acc[i][j] = (f32x4)0.0f;

    bf16x8 aaE0, aaE1, aaE2, aaE3, aaO0, aaO1, aaO2, aaO3;
    bf16x8 bbE0, bbE1, bbE2, bbE3, bbO0, bbO1, bbO2, bbO3;

    // ---- prologue: stage tile 0 into buf0 ----
    ST_A(0, 0) ST_B(0, 0) ST_A(0, 1) ST_B(0, 1)

#pragma unroll 1
    for (int T = 0; T < NT - 1; ++T) {
        const int bc = T & 1;
        tile_bar();                 // own DMA drained THEN barrier: all waves'
                                    // tile-T rows landed; buf bc^1 reads done
        ST_A(T + 1, 0) ST_B(T + 1, 0) ST_A(T + 1, 1) ST_B(T + 1, 1)
        BODY(bc)                    // full-tile drift window: waves overlap
    }
    {   const int bc = (NT - 1) & 1;
        tile_bar();
        BODY(bc)
    }

    // ---- epilogue: C/D layout col = lane&15, row = (lane>>4)*4 + reg ----
    float bv[4];
#pragma unroll
    for (int nf = 0; nf < 4; ++nf) bv[nf] = bias[o0 + wc * 64 + nf * 16 + l15];
#pragma unroll
    for (int mf = 0; mf < 8; ++mf) {
        const int t = t0 + wr * 128 + mf * 16 + q * 4;
#pragma unroll
        for (int nf = 0; nf < 4; ++nf) {
            const int o = o0 + wc * 64 + nf * 16 + l15;
#pragma unroll
            for (int r = 0; r < 4; ++r)
                C[(size_t)(t + r) * OUT_F + o] = acc[mf][nf][r] + bv[nf];
        }
    }
}

// ---------------- fp32 fallback (only if ws too small) ----------------
__global__ __launch_bounds__(256) void gemm_f32_fallback(const float* __restrict__ x,
                                                         const float* __restrict__ w,
                                                         const float* __restrict__ bias,
                                                         const int* __restrict__ mask,
                                                         float* __restrict__ out) {
    __shared__ float As[64][17];
    __shared__ float Bs[64][17];
    int bid = blockIdx.x;
    const int tiles_n = OUT_F / 64;
    int tm = bid / tiles_n, tn = bid % tiles_n;
    int t0 = tm * 64, o0 = tn * 64;
    int tid = threadIdx.x;
    int tx = tid & 15, ty = tid >> 4;
    int lrow = tid >> 2, lc4 = (tid & 3) * 4;
    float acc[4][4] = {};
    for (int k0 = 0; k0 < IN_F; k0 += 16) {
        float4 av = *(const float4*)&x[(size_t)(t0 + lrow) * IN_F + k0 + lc4];
        float4 bv = *(const float4*)&w[(size_t)(o0 + lrow) * IN_F + k0 + lc4];
        int mb = mask[((o0 + lrow) >> 4) * (IN_F / 16) + ((k0 + lc4) >> 4)];
        float s = mb ? 2.0f : 1.0f;
        As[lrow][lc4 + 0] = av.x; As[lrow][lc4 + 1] = av.y;
        As[lrow][lc4 + 2] = av.z; As[lrow][lc4 + 3] = av.w;
        Bs[lrow][lc4 + 0] = bv.x * s; Bs[lrow][lc4 + 1] = bv.y * s;
        Bs[lrow][lc4 + 2] = bv.z * s; Bs[lrow][lc4 + 3] = bv.w * s;
        __syncthreads();
#pragma unroll
        for (int kk = 0; kk < 16; ++kk) {
            float av2[4], bv2[4];
#pragma unroll
            for (int i = 0; i < 4; ++i) av2[i] = As[ty * 4 + i][kk];
#pragma unroll
            for (int j = 0; j < 4; ++j) bv2[j] = Bs[tx * 4 + j][kk];
#pragma unroll
            for (int i = 0; i < 4; ++i)
#pragma unroll
                for (int j = 0; j < 4; ++j) acc[i][j] += av2[i] * bv2[j];
        }
        __syncthreads();
    }
#pragma unroll
    for (int j = 0; j < 4; ++j) {
        int o = o0 + tx * 4 + j;
        float bv = bias[o];
#pragma unroll
        for (int i = 0; i < 4; ++i)
            out[(size_t)(t0 + ty * 4 + i) * OUT_F + o] = acc[i][j] + bv;
    }
}

extern "C" void kernel_launch(void* const* d_in, const int* in_sizes, int n_in,
                              void* d_out, int out_size, void* d_ws, size_t ws_size,
                              hipStream_t stream) {
    const float* x    = (const float*)d_in[0];
    const float* wgt  = (const float*)d_in[1];
    const float* bias = (const float*)d_in[2];
    const int*   mask = (const int*)d_in[3];
    float* out = (float*)d_out;

    size_t xb_bytes = (size_t)TOKENS * IN_F * 2;
    size_t wb_bytes = (size_t)OUT_F * IN_F * 2;

    if (ws_size >= xb_bytes + wb_bytes) {
        unsigned short* xb = (unsigned short*)d_ws;
        unsigned short* wb = (unsigned short*)((char*)d_ws + xb_bytes);
        hipLaunchKernelGGL(cvt_kernel, dim3(XBLOCKS + WBLOCKS), dim3(256), 0, stream,
                           x, wgt, mask, xb, wb);
        (void)hipFuncSetAttribute((const void*)gemm8_kernel,
                                  hipFuncAttributeMaxDynamicSharedMemorySize, 131072);
        hipLaunchKernelGGL(gemm8_kernel, dim3((TOKENS / BM) * (OUT_F / BN)), dim3(512),
                           131072, stream, xb, wb, bias, out);
    } else {
        hipLaunchKernelGGL(gemm_f32_fallback, dim3((TOKENS / 64) * (OUT_F / 64)), dim3(256), 0, stream,
                           x, wgt, bias, mask, out);
    }
}

// Round 11
// 281.950 us; speedup vs baseline: 1.0635x; 1.0635x over previous
//
#include <hip/hip_runtime.h>
#include <hip/hip_bf16.h>
#include <stdint.h>

#define TOKENS 8192
#define IN_F   4096
#define OUT_F  4096

typedef __attribute__((ext_vector_type(4))) float  f32x4;
typedef __attribute__((ext_vector_type(8))) __bf16 bf16x8;

__device__ __forceinline__ unsigned short f2bf(float f) {
    union { float f; uint32_t u; } c; c.f = f;
    uint32_t u = c.u;
    u += 0x7fffu + ((u >> 16) & 1);   // round-to-nearest-even
    return (unsigned short)(u >> 16);
}

__device__ __forceinline__ void load_lds_16(const void* gptr, void* lptr) {
    __builtin_amdgcn_global_load_lds(
        (const __attribute__((address_space(1))) unsigned int*)gptr,
        (__attribute__((address_space(3))) unsigned int*)lptr, 16, 0, 0);
}

// Staging guard: WAIT-then-BARRIER (own DMA drained, then barrier proves all
// waves' cooperative rows landed — R9's barrier-first order raced).
template<int N> __device__ __forceinline__ void vm_bar() {
    if constexpr (N == 4) asm volatile("s_waitcnt vmcnt(4)\ns_barrier" ::: "memory");
    else                  asm volatile("s_waitcnt vmcnt(0)\ns_barrier" ::: "memory");
}
// counted DS wait: oldest reads done, newer stay in flight under MFMA.
// rule #18: sched_barrier(0) so reg-only MFMAs can't hoist above the wait.
template<int N> __device__ __forceinline__ void lgkm() {
    if constexpr (N == 8)      asm volatile("s_waitcnt lgkmcnt(8)" ::: "memory");
    else if constexpr (N == 4) asm volatile("s_waitcnt lgkmcnt(4)" ::: "memory");
    else                       asm volatile("s_waitcnt lgkmcnt(0)" ::: "memory");
    __builtin_amdgcn_sched_barrier(0);
}

// ---------------- prep: x fp32 -> bf16 ----------------
__global__ __launch_bounds__(256) void cvt_x_kernel(const float* __restrict__ x,
                                                    unsigned short* __restrict__ xb, int n4) {
    int i = blockIdx.x * blockDim.x + threadIdx.x;
    int stride = gridDim.x * blockDim.x;
    for (; i < n4; i += stride) {
        float4 v = ((const float4*)x)[i];
        ushort4 o;
        o.x = f2bf(v.x); o.y = f2bf(v.y); o.z = f2bf(v.z); o.w = f2bf(v.w);
        ((ushort4*)xb)[i] = o;
    }
}

// ---------------- prep: W_eff = W*(1+mask) fp32 -> bf16 ----------------
__global__ __launch_bounds__(256) void cvt_w_kernel(const float* __restrict__ w,
                                                    const int* __restrict__ mask,
                                                    unsigned short* __restrict__ wb) {
    const int n4 = OUT_F * IN_F / 4;
    int i = blockIdx.x * blockDim.x + threadIdx.x;
    int stride = gridDim.x * blockDim.x;
    for (; i < n4; i += stride) {
        int elem = i * 4;
        int o = elem >> 12;
        int k = elem & (IN_F - 1);
        int mb = mask[(o >> 4) * (IN_F / 16) + (k >> 4)];
        float s = mb ? 2.0f : 1.0f;
        float4 v = ((const float4*)w)[i];
        ushort4 ov;
        ov.x = f2bf(v.x * s); ov.y = f2bf(v.y * s);
        ov.z = f2bf(v.z * s); ov.w = f2bf(v.w * s);
        ((ushort4*)wb)[i] = ov;
    }
}

// ------- 256x256 8-wave, 4 phases/K-tile, ds-read-ahead by one phase -------
// (R7 structure — measured optimum of this schedule family: 240us, MfmaUtil 53%)
// LDS (shorts): A[buf][ks] at buf*16384 + ks*8192 (256 rows x 32 shorts)
//               B[buf][ks] at 32768 + buf*16384 + ks*8192
// Swizzle: 8-short chunk c XOR (row>>1)&3 (pre-swizzled global source on
// stage, same XOR on fragment read) -> measured-0 conflicts (R3-R8).
#define BM 256
#define BN 256
#define BK 64
#define NT (IN_F / BK)   // 64

#define ST_A(T, H) {                                                           \
    const unsigned short* s_ = srcA + (size_t)(T) * BK + (H) * 32;             \
    unsigned short* d_ = sm + (((T) & 1) * 16384 + (H) * 8192) + dstL;         \
    load_lds_16(s_, d_);                                                       \
    load_lds_16(s_ + (size_t)128 * IN_F, d_ + 4096); }
#define ST_B(T, H) {                                                           \
    const unsigned short* s_ = srcB + (size_t)(T) * BK + (H) * 32;             \
    unsigned short* d_ = sm + (32768 + ((T) & 1) * 16384 + (H) * 8192) + dstL; \
    load_lds_16(s_, d_);                                                       \
    load_lds_16(s_ + (size_t)128 * IN_F, d_ + 4096); }

#define RDB4(R0, R1, R2, R3, BUF, KS) {                                        \
    const unsigned short* p_ = sm + 32768 + (BUF) * 16384 + (KS) * 8192 + b_base; \
    R0 = *(const bf16x8*)(p_);        R1 = *(const bf16x8*)(p_ + 512);         \
    R2 = *(const bf16x8*)(p_ + 1024); R3 = *(const bf16x8*)(p_ + 1536); }

#define RDA4(R0, R1, R2, R3, BUF, KS, MH) {                                    \
    const unsigned short* p_ = sm + (BUF) * 16384 + (KS) * 8192 + (MH) * 2048 + a_base; \
    R0 = *(const bf16x8*)(p_);        R1 = *(const bf16x8*)(p_ + 512);         \
    R2 = *(const bf16x8*)(p_ + 1024); R3 = *(const bf16x8*)(p_ + 1536); }

#define MM16(A0, A1, A2, A3, B0, B1, B2, B3, MH) {                             \
    __builtin_amdgcn_s_setprio(1);                                             \
    acc[(MH)*4+0][0] = __builtin_amdgcn_mfma_f32_16x16x32_bf16(A0, B0, acc[(MH)*4+0][0], 0, 0, 0); \
    acc[(MH)*4+0][1] = __builtin_amdgcn_mfma_f32_16x16x32_bf16(A0, B1, acc[(MH)*4+0][1], 0, 0, 0); \
    acc[(MH)*4+0][2] = __builtin_amdgcn_mfma_f32_16x16x32_bf16(A0, B2, acc[(MH)*4+0][2], 0, 0, 0); \
    acc[(MH)*4+0][3] = __builtin_amdgcn_mfma_f32_16x16x32_bf16(A0, B3, acc[(MH)*4+0][3], 0, 0, 0); \
    acc[(MH)*4+1][0] = __builtin_amdgcn_mfma_f32_16x16x32_bf16(A1, B0, acc[(MH)*4+1][0], 0, 0, 0); \
    acc[(MH)*4+1][1] = __builtin_amdgcn_mfma_f32_16x16x32_bf16(A1, B1, acc[(MH)*4+1][1], 0, 0, 0); \
    acc[(MH)*4+1][2] = __builtin_amdgcn_mfma_f32_16x16x32_bf16(A1, B2, acc[(MH)*4+1][2], 0, 0, 0); \
    acc[(MH)*4+1][3] = __builtin_amdgcn_mfma_f32_16x16x32_bf16(A1, B3, acc[(MH)*4+1][3], 0, 0, 0); \
    acc[(MH)*4+2][0] = __builtin_amdgcn_mfma_f32_16x16x32_bf16(A2, B0, acc[(MH)*4+2][0], 0, 0, 0); \
    acc[(MH)*4+2][1] = __builtin_amdgcn_mfma_f32_16x16x32_bf16(A2, B1, acc[(MH)*4+2][1], 0, 0, 0); \
    acc[(MH)*4+2][2] = __builtin_amdgcn_mfma_f32_16x16x32_bf16(A2, B2, acc[(MH)*4+2][2], 0, 0, 0); \
    acc[(MH)*4+2][3] = __builtin_amdgcn_mfma_f32_16x16x32_bf16(A2, B3, acc[(MH)*4+2][3], 0, 0, 0); \
    acc[(MH)*4+3][0] = __builtin_amdgcn_mfma_f32_16x16x32_bf16(A3, B0, acc[(MH)*4+3][0], 0, 0, 0); \
    acc[(MH)*4+3][1] = __builtin_amdgcn_mfma_f32_16x16x32_bf16(A3, B1, acc[(MH)*4+3][1], 0, 0, 0); \
    acc[(MH)*4+3][2] = __builtin_amdgcn_mfma_f32_16x16x32_bf16(A3, B2, acc[(MH)*4+3][2], 0, 0, 0); \
    acc[(MH)*4+3][3] = __builtin_amdgcn_mfma_f32_16x16x32_bf16(A3, B3, acc[(MH)*4+3][3], 0, 0, 0); \
    __builtin_amdgcn_s_setprio(0); }

__global__ __launch_bounds__(512, 2) void gemm8_kernel(const unsigned short* __restrict__ A,
                                                       const unsigned short* __restrict__ B,
                                                       const float* __restrict__ bias,
                                                       float* __restrict__ C) {
    extern __shared__ __align__(16) unsigned short sm[];   // 128KB dynamic

    const int tid  = threadIdx.x;
    const int lane = tid & 63;
    const int wid  = tid >> 6;
    const int wr   = wid >> 2;       // 0..1 -> 128-row span
    const int wc   = wid & 3;        // 0..3 -> 64-col span

    const int nwg = (TOKENS / BM) * (OUT_F / BN);   // 512, %8==0
    int bid = blockIdx.x;
    int swz = (bid & 7) * (nwg >> 3) + (bid >> 3);  // XCD-aware swizzle
    const int tiles_n = OUT_F / BN;                 // 16
    const int t0 = (swz / tiles_n) * BM;
    const int o0 = (swz % tiles_n) * BN;

    // ---- staging constants (pre-swizzled global source, wave-linear dest) ----
    const int srow = tid >> 2;                      // 0..127
    const int sc   = tid & 3;                       // 8-short chunk
    const int scs  = sc ^ ((srow >> 1) & 3);
    const unsigned short* srcA = A + (size_t)(t0 + srow) * IN_F + scs * 8;
    const unsigned short* srcB = B + (size_t)(o0 + srow) * IN_F + scs * 8;
    const int dstL = srow * 32 + sc * 8;

    // ---- fragment-read bases (shorts), same swizzle ----
    const int l15 = lane & 15, q = lane >> 4;
    const int qe = q ^ ((l15 >> 1) & 3);
    const int a_base = (wr * 128 + l15) * 32 + qe * 8;   // + mh*2048 + mf*512
    const int b_base = (wc * 64 + l15) * 32 + qe * 8;    // + nf*512

    f32x4 acc[8][4];
#pragma unroll
    for (int i = 0; i < 8; ++i)
#pragma unroll
        for (int j = 0; j < 4; ++j) acc[i][j] = (f32x4)0.0f;

    bf16x8 aaE0, aaE1, aaE2, aaE3, aaO0, aaO1, aaO2, aaO3;
    bf16x8 bbE0, bbE1, bbE2, bbE3, bbO0, bbO1, bbO2, bbO3;

    // ---- prologue: stage tile 0 (order A0,B0,A1,B1), guard, prime reads_p0 ----
    ST_A(0, 0) ST_B(0, 0) ST_A(0, 1) ST_B(0, 1)
    vm_bar<4>();                               // A0,B0 of tile0 landed
    RDB4(bbE0, bbE1, bbE2, bbE3, 0, 0)
    RDA4(aaE0, aaE1, aaE2, aaE3, 0, 0, 0)

#pragma unroll 1
    for (int T = 0; T < NT - 1; ++T) {
        const int bc = T & 1, nbc = bc ^ 1;
        // p0: MFMA(ks0,mh0) | readahead A(ks0,mh1) | stage A0(T+1)
        ST_A(T + 1, 0)
        RDA4(aaO0, aaO1, aaO2, aaO3, bc, 0, 1)
        lgkm<4>();
        MM16(aaE0, aaE1, aaE2, aaE3, bbE0, bbE1, bbE2, bbE3, 0)
        // p1: MFMA(ks0,mh1) | guard ks1 | readahead B(ks1)+A(ks1,mh0) | stage B0(T+1)
        ST_B(T + 1, 0)
        vm_bar<4>();                           // tile T's A1,B1 landed
        RDB4(bbO0, bbO1, bbO2, bbO3, bc, 1)
        RDA4(aaE0, aaE1, aaE2, aaE3, bc, 1, 0)
        lgkm<8>();
        MM16(aaO0, aaO1, aaO2, aaO3, bbE0, bbE1, bbE2, bbE3, 1)
        // p2: MFMA(ks1,mh0) | readahead A(ks1,mh1) | stage A1(T+1)
        ST_A(T + 1, 1)
        RDA4(aaO0, aaO1, aaO2, aaO3, bc, 1, 1)
        lgkm<4>();
        MM16(aaE0, aaE1, aaE2, aaE3, bbO0, bbO1, bbO2, bbO3, 0)
        // p3: MFMA(ks1,mh1) | guard T+1 ks0 | readahead next tile p0 | stage B1(T+1)
        ST_B(T + 1, 1)
        vm_bar<4>();                           // tile T+1's A0,B0 landed
        RDB4(bbE0, bbE1, bbE2, bbE3, nbc, 0)
        RDA4(aaE0, aaE1, aaE2, aaE3, nbc, 0, 0)
        lgkm<8>();
        MM16(aaO0, aaO1, aaO2, aaO3, bbO0, bbO1, bbO2, bbO3, 1)
    }
    {   // peeled last tile (bc = 1, no staging)
        RDA4(aaO0, aaO1, aaO2, aaO3, 1, 0, 1)
        lgkm<4>();
        MM16(aaE0, aaE1, aaE2, aaE3, bbE0, bbE1, bbE2, bbE3, 0)
        vm_bar<0>();                           // last tile's A1,B1 landed
        RDB4(bbO0, bbO1, bbO2, bbO3, 1, 1)
        RDA4(aaE0, aaE1, aaE2, aaE3, 1, 1, 0)
        lgkm<8>();
        MM16(aaO0, aaO1, aaO2, aaO3, bbE0, bbE1, bbE2, bbE3, 1)
        RDA4(aaO0, aaO1, aaO2, aaO3, 1, 1, 1)
        lgkm<4>();
        MM16(aaE0, aaE1, aaE2, aaE3, bbO0, bbO1, bbO2, bbO3, 0)
        lgkm<0>();
        MM16(aaO0, aaO1, aaO2, aaO3, bbO0, bbO1, bbO2, bbO3, 1)
    }

    // ---- epilogue: C/D layout col = lane&15, row = (lane>>4)*4 + reg ----
    // Non-temporal stores: C (128MB) is write-once — keep it from evicting
    // the L2/L3-resident A/B panels (xb+wb = 96MB fits L3).
    float bv[4];
#pragma unroll
    for (int nf = 0; nf < 4; ++nf) bv[nf] = bias[o0 + wc * 64 + nf * 16 + l15];
#pragma unroll
    for (int mf = 0; mf < 8; ++mf) {
        const int t = t0 + wr * 128 + mf * 16 + q * 4;
#pragma unroll
        for (int nf = 0; nf < 4; ++nf) {
            const int o = o0 + wc * 64 + nf * 16 + l15;
#pragma unroll
            for (int r = 0; r < 4; ++r)
                __builtin_nontemporal_store(acc[mf][nf][r] + bv[nf],
                                            &C[(size_t)(t + r) * OUT_F + o]);
        }
    }
}

// ---------------- fp32 fallback (only if ws too small) ----------------
__global__ __launch_bounds__(256) void gemm_f32_fallback(const float* __restrict__ x,
                                                         const float* __restrict__ w,
                                                         const float* __restrict__ bias,
                                                         const int* __restrict__ mask,
                                                         float* __restrict__ out) {
    __shared__ float As[64][17];
    __shared__ float Bs[64][17];
    int bid = blockIdx.x;
    const int tiles_n = OUT_F / 64;
    int tm = bid / tiles_n, tn = bid % tiles_n;
    int t0 = tm * 64, o0 = tn * 64;
    int tid = threadIdx.x;
    int tx = tid & 15, ty = tid >> 4;
    int lrow = tid >> 2, lc4 = (tid & 3) * 4;
    float acc[4][4] = {};
    for (int k0 = 0; k0 < IN_F; k0 += 16) {
        float4 av = *(const float4*)&x[(size_t)(t0 + lrow) * IN_F + k0 + lc4];
        float4 bv = *(const float4*)&w[(size_t)(o0 + lrow) * IN_F + k0 + lc4];
        int mb = mask[((o0 + lrow) >> 4) * (IN_F / 16) + ((k0 + lc4) >> 4)];
        float s = mb ? 2.0f : 1.0f;
        As[lrow][lc4 + 0] = av.x; As[lrow][lc4 + 1] = av.y;
        As[lrow][lc4 + 2] = av.z; As[lrow][lc4 + 3] = av.w;
        Bs[lrow][lc4 + 0] = bv.x * s; Bs[lrow][lc4 + 1] = bv.y * s;
        Bs[lrow][lc4 + 2] = bv.z * s; Bs[lrow][lc4 + 3] = bv.w * s;
        __syncthreads();
#pragma unroll
        for (int kk = 0; kk < 16; ++kk) {
            float av2[4], bv2[4];
#pragma unroll
            for (int i = 0; i < 4; ++i) av2[i] = As[ty * 4 + i][kk];
#pragma unroll
            for (int j = 0; j < 4; ++j) bv2[j] = Bs[tx * 4 + j][kk];
#pragma unroll
            for (int i = 0; i < 4; ++i)
#pragma unroll
                for (int j = 0; j < 4; ++j) acc[i][j] += av2[i] * bv2[j];
        }
        __syncthreads();
    }
#pragma unroll
    for (int j = 0; j < 4; ++j) {
        int o = o0 + tx * 4 + j;
        float bv = bias[o];
#pragma unroll
        for (int i = 0; i < 4; ++i)
            out[(size_t)(t0 + ty * 4 + i) * OUT_F + o] = acc[i][j] + bv;
    }
}

extern "C" void kernel_launch(void* const* d_in, const int* in_sizes, int n_in,
                              void* d_out, int out_size, void* d_ws, size_t ws_size,
                              hipStream_t stream) {
    const float* x    = (const float*)d_in[0];
    const float* wgt  = (const float*)d_in[1];
    const float* bias = (const float*)d_in[2];
    const int*   mask = (const int*)d_in[3];
    float* out = (float*)d_out;

    size_t xb_bytes = (size_t)TOKENS * IN_F * 2;
    size_t wb_bytes = (size_t)OUT_F * IN_F * 2;

    if (ws_size >= xb_bytes + wb_bytes) {
        unsigned short* xb = (unsigned short*)d_ws;
        unsigned short* wb = (unsigned short*)((char*)d_ws + xb_bytes);
        hipLaunchKernelGGL(cvt_x_kernel, dim3(2048), dim3(256), 0, stream, x, xb, TOKENS * IN_F / 4);
        hipLaunchKernelGGL(cvt_w_kernel, dim3(1024), dim3(256), 0, stream, wgt, mask, wb);
        (void)hipFuncSetAttribute((const void*)gemm8_kernel,
                                  hipFuncAttributeMaxDynamicSharedMemorySize, 131072);
        hipLaunchKernelGGL(gemm8_kernel, dim3((TOKENS / BM) * (OUT_F / BN)), dim3(512),
                           131072, stream, xb, wb, bias, out);
    } else {
        hipLaunchKernelGGL(gemm_f32_fallback, dim3((TOKENS / 64) * (OUT_F / 64)), dim3(256), 0, stream,
                           x, wgt, bias, mask, out);
    }
}